// Round 9
// baseline (69.344 us; speedup 1.0000x reference)
//
#include <hip/hip_runtime.h>
#include <hip/hip_bf16.h>
#include <math.h>

// TopKRouter: x (16384 x 2048) f32 @ gate_w^T (2048 x 64) -> top-2 + softmax.
// Output (f32): [indices as floats (N*2)] ++ [weights (N*2)].
//
// v9 = v8 minus pack_w: single kernel. A staged to LDS via global_load_lds
// (swizzled source, linear dest, depth-4 rotation); B loaded raw f32 from
// L2-resident w into 4 rotating register sets (same 5 VMEM/chunk/wave ->
// vmcnt(15) steady-state pipeline, peeled tail 15/10/5/0); B split to bf16
// hi/lo INSIDE compute (after the wait -> no early drain). 8 waves x
// (16 rows x 16 experts). 3-term split-bf16 MFMA (err ~1e-6). Shfl top-2.

constexpr int D_DIM = 2048;
constexpr int E_DIM = 64;
constexpr int BM    = 32;               // rows per block
constexpr int BKC   = 64;               // K per chunk
constexpr int NCH   = D_DIM / BKC;      // 32 chunks
constexpr int LPAD  = 68;

typedef __attribute__((ext_vector_type(8))) short s16x8;  // 8 bf16
typedef __attribute__((ext_vector_type(4))) float f32x4;  // MFMA C/D

static __device__ __forceinline__ short f2bf(float f) {
    __hip_bfloat16 h = __float2bfloat16(f);   // RNE
    return *reinterpret_cast<short*>(&h);
}
static __device__ __forceinline__ float b2f(short s) {
    union { unsigned u; float f; } x;
    x.u = ((unsigned)(unsigned short)s) << 16;
    return x.f;
}

template <int N> static __device__ __forceinline__ void waitvm() {
    asm volatile("s_waitcnt vmcnt(%0)" :: "n"(N) : "memory");
}

__global__ __launch_bounds__(512, 4)
void router_v9(const float* __restrict__ x,
               const float* __restrict__ w,
               float* __restrict__ out,
               int nrows) {
    __shared__ alignas(16) float smem[4][BM * BKC / 4 * 4];  // 4 x 8KB

    const int t    = threadIdx.x;
    const int lane = t & 63;
    const int wv   = t >> 6;            // 8 waves
    const int row0 = blockIdx.x * BM;
    const int l15  = lane & 15;
    const int k8   = lane >> 4;
    const int rsel = wv & 1;            // rows [16*rsel, +16)
    const int e0w  = (wv >> 1) * 16;    // experts [e0w, +16)
    const int ph   = blockIdx.x & (NCH - 1);

    // 4 rotating raw-f32 B sets: [p][s][half] (converted in compute)
    float4 B32[4][2][2];

    auto loadB = [&](int p, int c) {
        const int cc = (c + ph) & (NCH - 1);
        #pragma unroll
        for (int s = 0; s < 2; ++s) {
            const float* pw = w + (size_t)(e0w + l15) * D_DIM
                            + cc * BKC + (s * 4 + k8) * 8;
            B32[p][s][0] = *reinterpret_cast<const float4*>(pw);
            B32[p][s][1] = *reinterpret_cast<const float4*>(pw + 4);
        }
    };

    // A staging: wave wv stages rows [4wv, 4wv+4); linear LDS dest,
    // pre-swizzled global source (rule #21).
    auto stageA = [&](int p, int c) {
        const int cc = (c + ph) & (NCH - 1);
        const int r  = 4 * wv + (lane >> 4);
        const char* src = (const char*)x + (size_t)(row0 + r) * (D_DIM * 4)
                        + cc * 256 + ((l15 * 16) ^ ((r & 7) << 4));
        __builtin_amdgcn_global_load_lds(
            (const __attribute__((address_space(1))) void*)src,
            (__attribute__((address_space(3))) void*)((char*)&smem[p][0] + wv * 1024),
            16, 0, 0);
    };

    f32x4 acc;
    #pragma unroll
    for (int j = 0; j < 4; ++j) acc[j] = 0.f;

    auto compute = [&](int p) {
        const char* rp  = (const char*)&smem[p][0] + (16 * rsel + l15) * 256;
        const int   swz = ((16 * rsel + l15) & 7) << 4;
        #pragma unroll
        for (int s = 0; s < 2; ++s) {
            // ---- B: split raw f32 -> hi/lo bf16 (data ready post-wait) ----
            const float4 w0 = B32[p][s][0];
            const float4 w1 = B32[p][s][1];
            const float wvv[8] = {w0.x, w0.y, w0.z, w0.w, w1.x, w1.y, w1.z, w1.w};
            s16x8 bh, bl;
            #pragma unroll
            for (int j = 0; j < 8; ++j) {
                const short h = f2bf(wvv[j]);
                bh[j] = h;
                bl[j] = f2bf(wvv[j] - b2f(h));
            }
            // ---- A frag: 8 f32 of this lane's row from LDS, split hi/lo ----
            const int off = s * 128 + k8 * 32;
            const float4 v0 = *reinterpret_cast<const float4*>(rp + (off ^ swz));
            const float4 v1 = *reinterpret_cast<const float4*>(rp + ((off + 16) ^ swz));
            const float vv[8] = {v0.x, v0.y, v0.z, v0.w, v1.x, v1.y, v1.z, v1.w};
            s16x8 ah, al;
            #pragma unroll
            for (int j = 0; j < 8; ++j) {
                const short h = f2bf(vv[j]);
                ah[j] = h;
                al[j] = f2bf(vv[j] - b2f(h));
            }
            // ---- 3-term split MFMA ----
            acc = __builtin_amdgcn_mfma_f32_16x16x32_bf16(al, bh, acc, 0, 0, 0);
            acc = __builtin_amdgcn_mfma_f32_16x16x32_bf16(ah, bl, acc, 0, 0, 0);
            acc = __builtin_amdgcn_mfma_f32_16x16x32_bf16(ah, bh, acc, 0, 0, 0);
        }
    };

    // ---- prologue: chunks 0..3, 5 VMEM ops each per wave ----
    #pragma unroll
    for (int p = 0; p < 4; ++p) { loadB(p, p); stageA(p, p); }

    // ---- main: chunks 0..27, depth-4, vmcnt(15) steady state ----
    #pragma unroll 1
    for (int cq = 0; cq < 7; ++cq) {
        #pragma unroll
        for (int p = 0; p < 4; ++p) {
            waitvm<15>();
            __builtin_amdgcn_s_barrier();
            asm volatile("" ::: "memory");
            compute(p);
            asm volatile("s_waitcnt lgkmcnt(0)" ::: "memory");
            __builtin_amdgcn_s_barrier();
            asm volatile("" ::: "memory");
            const int c = cq * 4 + p + 4;
            loadB(p, c);
            stageA(p, c);
        }
    }
    // ---- tail: chunks 28..31, peeled waits ----
    waitvm<15>(); __builtin_amdgcn_s_barrier(); asm volatile("" ::: "memory"); compute(0);
    waitvm<10>(); __builtin_amdgcn_s_barrier(); asm volatile("" ::: "memory"); compute(1);
    waitvm<5>();  __builtin_amdgcn_s_barrier(); asm volatile("" ::: "memory"); compute(2);
    waitvm<0>();  __builtin_amdgcn_s_barrier(); asm volatile("" ::: "memory"); compute(3);
    __syncthreads();

    // ---- logits -> LDS (each (row,e) written once) ----
    float* lgs = &smem[0][0];                   // [32][68] = 8.7 KB
    #pragma unroll
    for (int j = 0; j < 4; ++j)
        lgs[(16 * rsel + k8 * 4 + j) * LPAD + e0w + l15] = acc[j];
    __syncthreads();

    // ---- per-row top-2 + softmax (waves 0..3, 8 rows each) ----
    if (wv < 4) {
        const int row = wv * 8 + (lane >> 3);
        const int seg = lane & 7;
        const float* rp = &lgs[row * LPAD + seg * 8];
        const float4 a  = *reinterpret_cast<const float4*>(rp);
        const float4 bq = *reinterpret_cast<const float4*>(rp + 4);
        const float sv[8] = {a.x, a.y, a.z, a.w, bq.x, bq.y, bq.z, bq.w};
        float m1 = sv[0]; int i1 = seg * 8;
        float m2 = -INFINITY; int i2 = 0;
        #pragma unroll
        for (int j = 1; j < 8; ++j) {
            const float v = sv[j]; const int idx = seg * 8 + j;
            if (v > m1)      { m2 = m1; i2 = i1; m1 = v; i1 = idx; }
            else if (v > m2) { m2 = v;  i2 = idx; }
        }
        #pragma unroll
        for (int d = 1; d < 8; d <<= 1) {
            const float M1 = __shfl_xor(m1, d); const int I1 = __shfl_xor(i1, d);
            const float M2 = __shfl_xor(m2, d); const int I2 = __shfl_xor(i2, d);
            const bool sw = (M1 > m1) || (M1 == m1 && I1 < i1);
            const float a1 = sw ? M1 : m1; const int j1 = sw ? I1 : i1;
            const float b1 = sw ? m1 : M1; const int kx = sw ? i1 : I1;
            const float a2 = sw ? M2 : m2; const int j2 = sw ? I2 : i2;
            const bool t2 = (b1 > a2) || (b1 == a2 && kx < j2);
            m1 = a1; i1 = j1;
            m2 = t2 ? b1 : a2; i2 = t2 ? kx : j2;
        }
        if (seg == 0) {
            const float e2v = expf(m2 - m1);
            const float sm  = 1.0f + e2v;
            const long  r   = row0 + row;
            const long  off = (long)nrows * 2;
            out[2 * r + 0]       = (float)i1;
            out[2 * r + 1]       = (float)i2;
            out[off + 2 * r + 0] = 1.0f / sm;
            out[off + 2 * r + 1] = e2v / sm;
        }
    }
}

extern "C" void kernel_launch(void* const* d_in, const int* in_sizes, int n_in,
                              void* d_out, int out_size, void* d_ws, size_t ws_size,
                              hipStream_t stream) {
    const float* x = (const float*)d_in[0];
    const float* w = (const float*)d_in[1];
    float* out = (float*)d_out;
    const int nrows = in_sizes[0] / D_DIM;            // 16384
    const int grid  = nrows / BM;                     // 512
    hipLaunchKernelGGL(router_v9, dim3(grid), dim3(512), 0, stream,
                       x, w, out, nrows);
}

// Round 12
// 42.039 us; speedup vs baseline: 1.6495x; 1.6495x over previous
//
#include <hip/hip_runtime.h>
#include <hip/hip_bf16.h>
#include <math.h>

// TopKRouter: x (16384 x 2048) f32 @ gate_w^T (2048 x 64) -> top-2 + softmax.
// Output (f32): [indices as floats (N*2)] ++ [weights (N*2)].
//
// v12 = v11 with the LDS size bug fixed: smem[2][4][BM*BKC] (2 grp x 4 buf x
// 8KB = 64KB), matching stageA's 8KB-per-buffer writes. (v11 had BM*BKC/4 =
// 2KB buffers -> stageA overflowed 6KB past each buffer -> garbage logits.)
//  - 8 waves = 2 concurrent K-streams (group kg: chunks kg*16+c) x 4 expert
//    groups; every packed-B byte read exactly once per block (512KB).
//  - wsb packed so each B load is ONE contiguous 1KB wave-run.
//  - A staged via global_load_lds (pre-swizzled source, linear dest);
//    6 VMEM/chunk/wave -> depth-4 counted pipeline vmcnt(18), tail 18/12/6/0.
//  - 3-term split-bf16 MFMA (err ~1e-6); 2-partial LDS reduce + shfl top-2.

constexpr int D_DIM = 2048;
constexpr int E_DIM = 64;
constexpr int BM    = 32;               // rows per block
constexpr int BKC   = 64;               // K per chunk (= 256 bytes/row)
constexpr int NCHG  = 16;               // chunks per K-stream group
constexpr int LPAD  = 68;

typedef __attribute__((ext_vector_type(8))) short s16x8;  // 8 bf16
typedef __attribute__((ext_vector_type(4))) float f32x4;  // MFMA C/D

static __device__ __forceinline__ short f2bf(float f) {
    __hip_bfloat16 h = __float2bfloat16(f);   // RNE
    return *reinterpret_cast<short*>(&h);
}
static __device__ __forceinline__ float b2f(short s) {
    union { unsigned u; float f; } x;
    x.u = ((unsigned)(unsigned short)s) << 16;
    return x.f;
}

template <int N> static __device__ __forceinline__ void waitvm() {
    asm volatile("s_waitcnt vmcnt(%0)" :: "n"(N) : "memory");
}

// pack w: per chunk cc (16KB): 16 x 1KB runs ordered [s(2)][hl(2)][eg(4)];
// run content = [k8(4)][l15(16)] x 16B -> wave reads base + lane*16.
__global__ __launch_bounds__(256, 1)
void pack_w(const float* __restrict__ w, short* __restrict__ wsb) {
    const int idx = blockIdx.x * 256 + threadIdx.x;   // 64*2048
    const int e = idx >> 11, k = idx & 2047;
    const float v = w[idx];
    const short hi = f2bf(v);
    const short lo = f2bf(v - b2f(hi));
    const int g = k >> 3, j = k & 7;
    const int cc = g >> 3, g7 = g & 7, s = g7 >> 2, k8g = g7 & 3;
    const int eg = e >> 4, l15e = e & 15;
    const int Q = cc * 16 + s * 8 + eg;               // hl=0 slot (1KB units)
    const size_t hi16 = ((size_t)Q * 4 + k8g) * 16 + l15e;        // 16B units
    const size_t lo16 = ((size_t)(Q + 4) * 4 + k8g) * 16 + l15e;  // hl=1
    wsb[hi16 * 8 + j] = hi;
    wsb[lo16 * 8 + j] = lo;
}

template <bool PACKED>
__global__ __launch_bounds__(512, 4)
void router_v12(const float* __restrict__ x,
                const float* __restrict__ w,
                const short* __restrict__ wsb,
                float* __restrict__ out,
                int nrows) {
    __shared__ alignas(16) float smem[2][4][BM * BKC];  // 2 grp x 4 buf x 8KB = 64KB

    const int t    = threadIdx.x;
    const int lane = t & 63;
    const int wv   = t >> 6;            // 8 waves
    const int kg   = wv >> 2;           // K-stream group 0/1
    const int eg   = wv & 3;            // expert group -> experts [16*eg,+16)
    const int row0 = blockIdx.x * BM;
    const int l15  = lane & 15;
    const int k8   = lane >> 4;
    const int e0w  = eg * 16;
    const int ph   = blockIdx.x & (NCHG - 1);
    const char* wsb_b = (const char*)wsb;

    s16x8 Bh[4][2], Bl[4][2];           // 4 rotating sets (static idx)

    auto loadB = [&](int p, int c) {
        const int cc = kg * NCHG + ((c + ph) & (NCHG - 1));
        const size_t cb = (size_t)cc * 16384;
        if constexpr (PACKED) {
            #pragma unroll
            for (int s = 0; s < 2; ++s) {
                const char* hb = wsb_b + cb + (size_t)(s * 8 + 0 + eg) * 1024 + lane * 16;
                const char* lb = wsb_b + cb + (size_t)(s * 8 + 4 + eg) * 1024 + lane * 16;
                Bh[p][s] = *reinterpret_cast<const s16x8*>(hb);
                Bl[p][s] = *reinterpret_cast<const s16x8*>(lb);
            }
        } else {
            #pragma unroll
            for (int s = 0; s < 2; ++s) {
                const float* pw = w + (size_t)(e0w + l15) * D_DIM
                                + cc * BKC + (s * 4 + k8) * 8;
                const float4 w0 = *reinterpret_cast<const float4*>(pw);
                const float4 w1 = *reinterpret_cast<const float4*>(pw + 4);
                const float wvv[8] = {w0.x, w0.y, w0.z, w0.w, w1.x, w1.y, w1.z, w1.w};
                #pragma unroll
                for (int j = 0; j < 8; ++j) {
                    const short h = f2bf(wvv[j]);
                    Bh[p][s][j] = h;
                    Bl[p][s][j] = f2bf(wvv[j] - b2f(h));
                }
            }
        }
    };

    // A staging: group kg's 4 waves stage the 8KB chunk; wave stages rows
    // [eg*8, eg*8+8) as 2 x 1KB. Linear LDS dest, pre-swizzled source.
    auto stageA = [&](int p, int c) {
        const int cc = kg * NCHG + ((c + ph) & (NCHG - 1));
        #pragma unroll
        for (int q = 0; q < 2; ++q) {
            const int r = eg * 8 + q * 4 + (lane >> 4);
            const char* src = (const char*)x + (size_t)(row0 + r) * (D_DIM * 4)
                            + cc * 256 + ((l15 * 16) ^ ((r & 7) << 4));
            __builtin_amdgcn_global_load_lds(
                (const __attribute__((address_space(1))) void*)src,
                (__attribute__((address_space(3))) void*)
                    ((char*)&smem[kg][p][0] + (eg * 8 + q * 4) * 256),
                16, 0, 0);
        }
    };

    f32x4 acc[2];
    #pragma unroll
    for (int mf = 0; mf < 2; ++mf)
        #pragma unroll
        for (int j = 0; j < 4; ++j) acc[mf][j] = 0.f;

    auto compute = [&](int p) {
        const char* bufb = (const char*)&smem[kg][p][0];
        #pragma unroll
        for (int mf = 0; mf < 2; ++mf) {
            const int r   = mf * 16 + l15;
            const char* rp = bufb + r * 256;
            const int swz = (r & 7) << 4;
            #pragma unroll
            for (int s = 0; s < 2; ++s) {
                const int off = s * 128 + k8 * 32;
                const float4 v0 = *reinterpret_cast<const float4*>(rp + (off ^ swz));
                const float4 v1 = *reinterpret_cast<const float4*>(rp + ((off + 16) ^ swz));
                const float vv[8] = {v0.x, v0.y, v0.z, v0.w, v1.x, v1.y, v1.z, v1.w};
                s16x8 ah, al;
                #pragma unroll
                for (int j = 0; j < 8; ++j) {
                    const short h = f2bf(vv[j]);
                    ah[j] = h;
                    al[j] = f2bf(vv[j] - b2f(h));
                }
                acc[mf] = __builtin_amdgcn_mfma_f32_16x16x32_bf16(al, Bh[p][s], acc[mf], 0, 0, 0);
                acc[mf] = __builtin_amdgcn_mfma_f32_16x16x32_bf16(ah, Bl[p][s], acc[mf], 0, 0, 0);
                acc[mf] = __builtin_amdgcn_mfma_f32_16x16x32_bf16(ah, Bh[p][s], acc[mf], 0, 0, 0);
            }
        }
    };

    // ---- prologue: chunks 0..3 of this group's stream (6 VMEM each/wave) ----
    #pragma unroll
    for (int p = 0; p < 4; ++p) { loadB(p, p); stageA(p, p); }

    // ---- main: c = 0..11, depth-4, vmcnt(18) steady state ----
    #pragma unroll 1
    for (int cq = 0; cq < 3; ++cq) {
        #pragma unroll
        for (int p = 0; p < 4; ++p) {
            waitvm<18>();
            __builtin_amdgcn_s_barrier();
            asm volatile("" ::: "memory");
            compute(p);
            asm volatile("s_waitcnt lgkmcnt(0)" ::: "memory");
            __builtin_amdgcn_s_barrier();
            asm volatile("" ::: "memory");
            const int c = cq * 4 + p + 4;
            loadB(p, c);
            stageA(p, c);
        }
    }
    // ---- tail: chunks 12..15, peeled waits ----
    waitvm<18>(); __builtin_amdgcn_s_barrier(); asm volatile("" ::: "memory"); compute(0);
    waitvm<12>(); __builtin_amdgcn_s_barrier(); asm volatile("" ::: "memory"); compute(1);
    waitvm<6>();  __builtin_amdgcn_s_barrier(); asm volatile("" ::: "memory"); compute(2);
    waitvm<0>();  __builtin_amdgcn_s_barrier(); asm volatile("" ::: "memory"); compute(3);
    __syncthreads();

    // ---- partials -> LDS: lgs[kg][row][e] (17.4 KB, aliases bufs) ----
    float* lgs = &smem[0][0][0];
    #pragma unroll
    for (int mf = 0; mf < 2; ++mf)
        #pragma unroll
        for (int j = 0; j < 4; ++j)
            lgs[((size_t)kg * BM + mf * 16 + k8 * 4 + j) * LPAD + e0w + l15] = acc[mf][j];
    __syncthreads();

    // ---- per-row top-2 + softmax (waves 0..3, 8 rows each) ----
    if (wv < 4) {
        const int row = wv * 8 + (lane >> 3);
        const int seg = lane & 7;
        const float* r0 = &lgs[(size_t)row * LPAD + seg * 8];
        const float* r1 = &lgs[((size_t)BM + row) * LPAD + seg * 8];
        const float4 a0 = *reinterpret_cast<const float4*>(r0);
        const float4 b0 = *reinterpret_cast<const float4*>(r0 + 4);
        const float4 a1 = *reinterpret_cast<const float4*>(r1);
        const float4 b1 = *reinterpret_cast<const float4*>(r1 + 4);
        const float sv[8] = {a0.x + a1.x, a0.y + a1.y, a0.z + a1.z, a0.w + a1.w,
                             b0.x + b1.x, b0.y + b1.y, b0.z + b1.z, b0.w + b1.w};
        float m1 = sv[0]; int i1 = seg * 8;
        float m2 = -INFINITY; int i2 = 0;
        #pragma unroll
        for (int j = 1; j < 8; ++j) {
            const float v = sv[j]; const int idx = seg * 8 + j;
            if (v > m1)      { m2 = m1; i2 = i1; m1 = v; i1 = idx; }
            else if (v > m2) { m2 = v;  i2 = idx; }
        }
        #pragma unroll
        for (int d = 1; d < 8; d <<= 1) {
            const float M1 = __shfl_xor(m1, d); const int I1 = __shfl_xor(i1, d);
            const float M2 = __shfl_xor(m2, d); const int I2 = __shfl_xor(i2, d);
            const bool sw = (M1 > m1) || (M1 == m1 && I1 < i1);
            const float a_1 = sw ? M1 : m1; const int j1 = sw ? I1 : i1;
            const float b_1 = sw ? m1 : M1; const int kx = sw ? i1 : I1;
            const float a_2 = sw ? M2 : m2; const int j2 = sw ? I2 : i2;
            const bool t2 = (b_1 > a_2) || (b_1 == a_2 && kx < j2);
            m1 = a_1; i1 = j1;
            m2 = t2 ? b_1 : a_2; i2 = t2 ? kx : j2;
        }
        if (seg == 0) {
            const float e2v = expf(m2 - m1);
            const float sm  = 1.0f + e2v;
            const long  r   = row0 + row;
            const long  off = (long)nrows * 2;
            out[2 * r + 0]       = (float)i1;
            out[2 * r + 1]       = (float)i2;
            out[off + 2 * r + 0] = 1.0f / sm;
            out[off + 2 * r + 1] = e2v / sm;
        }
    }
}

extern "C" void kernel_launch(void* const* d_in, const int* in_sizes, int n_in,
                              void* d_out, int out_size, void* d_ws, size_t ws_size,
                              hipStream_t stream) {
    const float* x = (const float*)d_in[0];
    const float* w = (const float*)d_in[1];
    float* out = (float*)d_out;
    short* wsb = (short*)d_ws;
    const int nrows = in_sizes[0] / D_DIM;            // 16384
    const int grid  = nrows / BM;                     // 512
    const bool packed = ws_size >= (size_t)(E_DIM * D_DIM) * 2 * sizeof(short);

    if (packed) {
        hipLaunchKernelGGL(pack_w, dim3(E_DIM * D_DIM / 256), dim3(256), 0, stream, w, wsb);
        hipLaunchKernelGGL(router_v12<true>, dim3(grid), dim3(512), 0, stream,
                           x, w, wsb, out, nrows);
    } else {
        hipLaunchKernelGGL(router_v12<false>, dim3(grid), dim3(512), 0, stream,
                           x, w, wsb, out, nrows);
    }
}